// Round 12
// baseline (187.966 us; speedup 1.0000x reference)
//
#include <hip/hip_runtime.h>

typedef unsigned short ushort_t;
typedef unsigned int uint_t;
typedef __attribute__((ext_vector_type(8))) short short8;   // 8 x bf16 (4 VGPRs)
typedef __attribute__((ext_vector_type(4))) float f32x4;

#define B_   128
#define S_   1024
#define H_   256
#define T_   10
#define NEG_INF_ -1e8f

static __device__ __forceinline__ ushort_t f2bf(float x) {
    unsigned int u = __float_as_uint(x);
    unsigned int r = u + 0x7FFFu + ((u >> 16) & 1u);   // RNE
    return (ushort_t)(r >> 16);
}
static __device__ __forceinline__ float bflo(uint_t w) {
    return __uint_as_float(w << 16);
}
static __device__ __forceinline__ float bfhi(uint_t w) {
    return __uint_as_float(w & 0xFFFF0000u);
}
static __device__ __forceinline__ float sigf(float x) {
    return 1.0f / (1.0f + __expf(-x));
}
static __device__ __forceinline__ float tanh_acc(float x) {
    return 2.0f / (1.0f + __expf(-2.0f * x)) - 1.0f;
}
// clamped odd poly tanh: 5 VALU, |err|<~0.025 (threshold 2e6)
static __device__ __forceinline__ float tanh_fast(float x) {
    float u = x * x;
    float p = fmaf(0.019063f, u, -0.18852f);
    p = fmaf(p, u, 0.93106f);
    float r = x * p;
    return __builtin_amdgcn_fmed3f(r, -1.0f, 1.0f);
}
static __device__ __forceinline__ short8 pack_bf8(float4 a, float4 b) {
    short8 r;
    r[0] = (short)f2bf(a.x); r[1] = (short)f2bf(a.y);
    r[2] = (short)f2bf(a.z); r[3] = (short)f2bf(a.w);
    r[4] = (short)f2bf(b.x); r[5] = (short)f2bf(b.y);
    r[6] = (short)f2bf(b.z); r[7] = (short)f2bf(b.w);
    return r;
}

// ---------------------------------------------------------------------------
// prep_transpose: 7 weight planes (ih_r/z/n, hh_r/z/n, q) 256x256 fp32 ->
// transposed bf16-pair planes P2[c2][j]. 112 blocks.
// ---------------------------------------------------------------------------
__global__ void prep_transpose(const float* __restrict__ W_ih,
                               const float* __restrict__ W_hh,
                               const float* __restrict__ Wq,
                               uint_t* __restrict__ planes) {
    __shared__ float lds[64][65];
    const int p = blockIdx.x >> 4, tile = blockIdx.x & 15;
    const int j0 = (tile >> 2) * 64, c0 = (tile & 3) * 64;
    const float* src;
    if (p < 3)      src = W_ih + (size_t)p * 65536;
    else if (p < 6) src = W_hh + (size_t)(p - 3) * 65536;
    else            src = Wq;
    uint_t* dst = planes + (size_t)p * 32768;
    const int tid = threadIdx.x;
#pragma unroll
    for (int p4 = 0; p4 < 4; ++p4) {
        int i = p4 * 256 + tid;
        int jj = i >> 4, cc4 = (i & 15) * 4;
        float4 v = *((const float4*)&src[(size_t)(j0 + jj) * 256 + c0 + cc4]);
        lds[jj][cc4]     = v.x;
        lds[jj][cc4 + 1] = v.y;
        lds[jj][cc4 + 2] = v.z;
        lds[jj][cc4 + 3] = v.w;
    }
    __syncthreads();
#pragma unroll
    for (int p8 = 0; p8 < 8; ++p8) {
        int i = p8 * 256 + tid;
        int c2 = i >> 6, j = i & 63;
        float lo = lds[j][c2 * 2], hi = lds[j][c2 * 2 + 1];
        uint_t val = (uint_t)f2bf(lo) | ((uint_t)f2bf(hi) << 16);
        dst[(size_t)(c0 / 2 + c2) * 256 + j0 + j] = val;
    }
}

// ---------------------------------------------------------------------------
// prep_small: Wd -> bf16 row-major, mask output. grid = 768*256 exactly.
// ---------------------------------------------------------------------------
__global__ void prep_small(const float* __restrict__ Wd, const int* __restrict__ slen,
                           ushort_t* __restrict__ Wd_bf, float* __restrict__ out_mask) {
    int i = blockIdx.x * 256 + threadIdx.x;
    if (i < 65536) { Wd_bf[i] = f2bf(Wd[i]); return; }
    i -= 65536;
    int b = i >> 10, s = i & 1023;
    out_mask[i] = (s >= slen[b]) ? 1.0f : 0.0f;
}

// ---------------------------------------------------------------------------
// gru_all: 128 blocks x 512 threads, split-K, register-batched loads.
// (unchanged from R8/R10 -- part of the 179us config)
// ---------------------------------------------------------------------------
__global__ __launch_bounds__(512) void gru_all(
        const float* __restrict__ s0, const float* __restrict__ h0,
        const float* __restrict__ doc, const int* __restrict__ tgt,
        const uint_t* __restrict__ planes, const float* __restrict__ b_ih,
        const float* __restrict__ b_hh, const float* __restrict__ bq,
        float* __restrict__ targets) {
    __shared__ float xs[T_][256];
    __shared__ float hs[256];
    __shared__ float pr[256], pz[256], pn[256], pq[256];
    const int b = blockIdx.x;
    const int tid = threadIdx.x;
    const int j = tid & 255, half = tid >> 8;

    const uint_t* ihr = planes;
    const uint_t* ihz = planes + 32768;
    const uint_t* ihn = planes + 2 * 32768;
    const uint_t* hhr = planes + 3 * 32768;
    const uint_t* hhz = planes + 4 * 32768;
    const uint_t* hhn = planes + 5 * 32768;
    const uint_t* qT  = planes + 6 * 32768;

    for (int i = tid; i < 640; i += 512) {
        int t = i >> 6, c4 = i & 63;
        const float* src;
        if (t == 0) src = s0 + (size_t)b * H_;
        else {
            int idx = tgt[b * T_ + t - 1];
            if (idx < 0) idx = 0;
            src = doc + ((size_t)b * S_ + idx) * H_;
        }
        ((float4*)&xs[t][0])[c4] = ((const float4*)src)[c4];
    }
    if (half == 0) hs[j] = h0[(size_t)b * H_ + j];
    const float bhr = b_hh[j], bhz = b_hh[j + 256], bhn = b_hh[j + 512];
    const float bqj = bq[j];
    const float bihr = b_ih[j], bihz = b_ih[j + 256], bihn = b_ih[j + 512];
    __syncthreads();

    float g_r[5], g_z[5], g_n[5];
#pragma unroll
    for (int u = 0; u < 5; ++u) { g_r[u] = bihr; g_z[u] = bihz; g_n[u] = bihn; }
    const int tbase = half * 5;
#pragma unroll 1
    for (int bb = 0; bb < 16; ++bb) {
        uint_t wr8[8], wz8[8], wn8[8];
#pragma unroll
        for (int v = 0; v < 8; ++v) {
            int c2 = bb * 8 + v;
            wr8[v] = ihr[c2 * 256 + j];
            wz8[v] = ihz[c2 * 256 + j];
            wn8[v] = ihn[c2 * 256 + j];
        }
#pragma unroll
        for (int v = 0; v < 8; ++v) {
            int c2 = bb * 8 + v;
            float wr0 = bflo(wr8[v]), wr1 = bfhi(wr8[v]);
            float wz0 = bflo(wz8[v]), wz1 = bfhi(wz8[v]);
            float wn0 = bflo(wn8[v]), wn1 = bfhi(wn8[v]);
#pragma unroll
            for (int u = 0; u < 5; ++u) {
                float2 x2 = *((const float2*)&xs[tbase + u][c2 * 2]);
                g_r[u] = fmaf(wr0, x2.x, g_r[u]); g_r[u] = fmaf(wr1, x2.y, g_r[u]);
                g_z[u] = fmaf(wz0, x2.x, g_z[u]); g_z[u] = fmaf(wz1, x2.y, g_z[u]);
                g_n[u] = fmaf(wn0, x2.x, g_n[u]); g_n[u] = fmaf(wn1, x2.y, g_n[u]);
            }
        }
    }

    const int c2base = half * 64;
    const uint_t* hhr_h = hhr + (size_t)c2base * 256 + j;
    const uint_t* hhz_h = hhz + (size_t)c2base * 256 + j;
    const uint_t* hhn_h = hhn + (size_t)c2base * 256 + j;
    const uint_t* qT_h  = qT  + (size_t)c2base * 256 + j;

#pragma unroll
    for (int t = 0; t < T_; ++t) {
        const bool holder = (half == (t >= 5 ? 1 : 0));
        const int u = (t < 5) ? t : t - 5;
        float ar = 0.f, az = 0.f, an = 0.f;
#pragma unroll 1
        for (int bb = 0; bb < 8; ++bb) {
            uint_t wr8[8], wz8[8], wn8[8];
#pragma unroll
            for (int v = 0; v < 8; ++v) {
                int c2i = bb * 8 + v;
                wr8[v] = hhr_h[c2i * 256];
                wz8[v] = hhz_h[c2i * 256];
                wn8[v] = hhn_h[c2i * 256];
            }
#pragma unroll
            for (int v = 0; v < 8; ++v) {
                int c2i = bb * 8 + v;
                float2 h2 = *((const float2*)&hs[(c2base + c2i) * 2]);
                ar = fmaf(bflo(wr8[v]), h2.x, ar); ar = fmaf(bfhi(wr8[v]), h2.y, ar);
                az = fmaf(bflo(wz8[v]), h2.x, az); az = fmaf(bfhi(wz8[v]), h2.y, az);
                an = fmaf(bflo(wn8[v]), h2.x, an); an = fmaf(bfhi(wn8[v]), h2.y, an);
            }
        }
        if (!holder) { pr[j] = ar; pz[j] = az; pn[j] = an; }
        __syncthreads();
        if (holder) {
            float art = ar + pr[j] + bhr;
            float azt = az + pz[j] + bhz;
            float ant = an + pn[j] + bhn;
            float r = sigf(g_r[u] + art);
            float z = sigf(g_z[u] + azt);
            float n = tanh_acc(fmaf(r, ant, g_n[u]));
            float hold = hs[j];
            hs[j] = fmaf(z, hold - n, n);
        }
        __syncthreads();
        float q = 0.f;
#pragma unroll 1
        for (int bb = 0; bb < 4; ++bb) {
            uint_t wq16[16];
#pragma unroll
            for (int v = 0; v < 16; ++v)
                wq16[v] = qT_h[(bb * 16 + v) * 256];
#pragma unroll
            for (int v = 0; v < 16; ++v) {
                int c2i = bb * 16 + v;
                float2 h2 = *((const float2*)&hs[(c2base + c2i) * 2]);
                q = fmaf(bflo(wq16[v]), h2.x, q); q = fmaf(bfhi(wq16[v]), h2.y, q);
            }
        }
        if (!holder) pq[j] = q;
        __syncthreads();
        if (holder) targets[((size_t)t * B_ + b) * H_ + j] = q + pq[j] + bqj;
    }
}

// ---------------------------------------------------------------------------
// energy: R10 body (2-tile block, Wd prefetch pipeline, scalar tanh_fast)
// + EARLY-OUT: tiles entirely beyond sent_length write constant NEG_INF and
// exit (reference output there is exactly mask*NEG_INF = -1e8f). ~44% of
// blocks become trivial for slen ~ U(1,1024) -> ~2x less energy compute.
// D layout: col(lane&15)=s, row(g*4+rr)=k.
// ---------------------------------------------------------------------------
__global__ __launch_bounds__(256, 3) void energy_kernel(
        const float* __restrict__ doc, const ushort_t* __restrict__ Wd_bf,
        const float* __restrict__ targets, const float* __restrict__ bd,
        const float* __restrict__ Ws, const float* __restrict__ bs,
        const int* __restrict__ slenp, float* __restrict__ out) {
    __shared__ float tg[T_][256];
    __shared__ float ws_l[256], bd_l[256];
    const int bid = blockIdx.x;
    const int b = bid >> 3, st = bid & 7;
    const int tid = threadIdx.x;

    const int slen = slenp[b];

    // ---- early-out: whole 128-row tile is masked -> constant output ----
    if (st * 128 >= slen) {
        float* obase = out + (size_t)b * S_ + st * 128;
#pragma unroll
        for (int i = tid; i < 1280; i += 256) {
            int t = i >> 7, sl = i & 127;
            obase[(size_t)t * B_ * S_ + sl] = NEG_INF_;
        }
        return;
    }

    for (int i = tid; i < 640; i += 256) {
        int t = i >> 6, k4 = i & 63;
        ((float4*)&tg[t][0])[k4] = *((const float4*)&targets[((size_t)t * B_ + b) * H_ + k4 * 4]);
    }
    if (tid < 64) ((float4*)ws_l)[tid] = ((const float4*)Ws)[tid];
    else if (tid < 128) ((float4*)bd_l)[tid - 64] = ((const float4*)bd)[tid - 64];

    const int lane = tid & 63, w = tid >> 6;
    const int r16 = lane & 15, g = lane >> 4;

    const int s0_loc = st * 128 + w * 16 + r16;
    const float* drow0 = doc + ((size_t)b * S_ + s0_loc) * H_ + g * 8;
    const float* drow1 = drow0 + (size_t)64 * H_;
    short8 bdoc0[8], bdoc1[8];
#pragma unroll
    for (int ks = 0; ks < 8; ++ks) {
        float4 v0 = *((const float4*)(drow0 + ks * 32));
        float4 v1 = *((const float4*)(drow0 + ks * 32 + 4));
        bdoc0[ks] = pack_bf8(v0, v1);
        float4 u0 = *((const float4*)(drow1 + ks * 32));
        float4 u1 = *((const float4*)(drow1 + ks * 32 + 4));
        bdoc1[ks] = pack_bf8(u0, u1);
    }
    __syncthreads();

    float e0[T_], e1[T_];
#pragma unroll
    for (int t = 0; t < T_; ++t) { e0[t] = 0.f; e1[t] = 0.f; }

    const ushort_t* wbase = Wd_bf + (size_t)r16 * H_ + g * 8;
    const int kq = g * 4;

    // prologue: load nt=0 fragments
    short8 awd[8];
#pragma unroll
    for (int ks = 0; ks < 8; ++ks) awd[ks] = *((const short8*)(wbase + ks * 32));

#pragma unroll 1
    for (int nt = 0; nt < 16; ++nt) {
        const int k0 = nt * 16 + kq;

        // prefetch nt+1's fragments BEFORE compute/epilogue (latency hides)
        short8 awn[8];
        if (nt < 15) {
            const ushort_t* wnext = wbase + (size_t)((nt + 1) * 16) * H_;
#pragma unroll
            for (int ks = 0; ks < 8; ++ks) awn[ks] = *((const short8*)(wnext + ks * 32));
        }

        f32x4 bd4 = *((const f32x4*)&bd_l[k0]);
        f32x4 a00 = bd4;
        f32x4 a01 = {0.f, 0.f, 0.f, 0.f};
        f32x4 a10 = bd4;
        f32x4 a11 = {0.f, 0.f, 0.f, 0.f};
#pragma unroll
        for (int ks = 0; ks < 4; ++ks) {
            a00 = __builtin_amdgcn_mfma_f32_16x16x32_bf16(awd[ks],     bdoc0[ks],     a00, 0, 0, 0);
            a01 = __builtin_amdgcn_mfma_f32_16x16x32_bf16(awd[ks + 4], bdoc0[ks + 4], a01, 0, 0, 0);
            a10 = __builtin_amdgcn_mfma_f32_16x16x32_bf16(awd[ks],     bdoc1[ks],     a10, 0, 0, 0);
            a11 = __builtin_amdgcn_mfma_f32_16x16x32_bf16(awd[ks + 4], bdoc1[ks + 4], a11, 0, 0, 0);
        }
        f32x4 pA = a00 + a01;
        f32x4 pB = a10 + a11;
        f32x4 ws4 = *((const f32x4*)&ws_l[k0]);
#pragma unroll
        for (int t = 0; t < T_; ++t) {
            f32x4 tg4 = *((const f32x4*)&tg[t][k0]);
#pragma unroll
            for (int rr = 0; rr < 4; ++rr) {
                e0[t] = fmaf(tanh_fast(pA[rr] + tg4[rr]), ws4[rr], e0[t]);
                e1[t] = fmaf(tanh_fast(pB[rr] + tg4[rr]), ws4[rr], e1[t]);
            }
        }

        // rotate prefetched fragments in
#pragma unroll
        for (int ks = 0; ks < 8; ++ks) awd[ks] = awn[ks];
    }

    // reduce over g (lane bits 4,5)
#pragma unroll
    for (int t = 0; t < T_; ++t) {
        e0[t] += __shfl_xor(e0[t], 16);
        e0[t] += __shfl_xor(e0[t], 32);
        e1[t] += __shfl_xor(e1[t], 16);
        e1[t] += __shfl_xor(e1[t], 32);
    }

    const float bs0 = bs[0];
    const bool pad0 = (s0_loc >= slen);
    const bool pad1 = (s0_loc + 64 >= slen);
    float* obase = out + (size_t)b * S_ + s0_loc;
#pragma unroll
    for (int tt = g; tt < T_; tt += 4) {
        obase[(size_t)tt * B_ * S_]      = pad0 ? NEG_INF_ : (e0[tt] + bs0);
        obase[(size_t)tt * B_ * S_ + 64] = pad1 ? NEG_INF_ : (e1[tt] + bs0);
    }
}

// ---------------------------------------------------------------------------
extern "C" void kernel_launch(void* const* d_in, const int* in_sizes, int n_in,
                              void* d_out, int out_size, void* d_ws, size_t ws_size,
                              hipStream_t stream) {
    (void)in_sizes; (void)n_in; (void)out_size; (void)ws_size;
    const float* s0   = (const float*)d_in[0];
    const float* h0   = (const float*)d_in[1];
    const float* doc  = (const float*)d_in[2];
    const float* W_ih = (const float*)d_in[3];
    const float* W_hh = (const float*)d_in[4];
    const float* b_ih = (const float*)d_in[5];
    const float* b_hh = (const float*)d_in[6];
    const float* Wq   = (const float*)d_in[7];
    const float* bq   = (const float*)d_in[8];
    const float* Wd   = (const float*)d_in[9];
    const float* bd   = (const float*)d_in[10];
    const float* Ws   = (const float*)d_in[11];
    const float* bs   = (const float*)d_in[12];
    const int*   tgt  = (const int*)d_in[13];
    const int*   slen = (const int*)d_in[14];

    float* out_score = (float*)d_out;                       // [10][128][1024]
    float* out_mask  = out_score + T_ * B_ * S_;            // [128][1024]

    char* ws = (char*)d_ws;
    uint_t*   planes  = (uint_t*)(ws + 0);                  // 917504 B
    ushort_t* Wd_bf   = (ushort_t*)(ws + 917504);           // 131072 B
    float*    targets = (float*)(ws + 1048576);             // 1310720 B

    prep_transpose<<<112, 256, 0, stream>>>(W_ih, W_hh, Wq, planes);
    prep_small<<<768, 256, 0, stream>>>(Wd, slen, Wd_bf, out_mask);
    gru_all<<<128, 512, 0, stream>>>(s0, h0, doc, tgt, planes, b_ih, b_hh, bq, targets);
    energy_kernel<<<1024, 256, 0, stream>>>(doc, Wd_bf, targets, bd, Ws, bs, slen, out_score);
}

// Round 13
// 161.589 us; speedup vs baseline: 1.1632x; 1.1632x over previous
//
#include <hip/hip_runtime.h>

typedef unsigned short ushort_t;
typedef unsigned int uint_t;
typedef __attribute__((ext_vector_type(8))) short short8;   // 8 x bf16 (4 VGPRs)
typedef __attribute__((ext_vector_type(4))) float f32x4;

#define B_   128
#define S_   1024
#define H_   256
#define T_   10
#define NEG_INF_ -1e8f

static __device__ __forceinline__ ushort_t f2bf(float x) {
    unsigned int u = __float_as_uint(x);
    unsigned int r = u + 0x7FFFu + ((u >> 16) & 1u);   // RNE
    return (ushort_t)(r >> 16);
}
static __device__ __forceinline__ float bflo(uint_t w) {
    return __uint_as_float(w << 16);
}
static __device__ __forceinline__ float bfhi(uint_t w) {
    return __uint_as_float(w & 0xFFFF0000u);
}
static __device__ __forceinline__ float sigf(float x) {
    return 1.0f / (1.0f + __expf(-x));
}
static __device__ __forceinline__ float tanh_acc(float x) {
    return 2.0f / (1.0f + __expf(-2.0f * x)) - 1.0f;
}
// clamped odd poly tanh: 5 VALU, |err|<~0.025 (threshold 2e6)
static __device__ __forceinline__ float tanh_fast(float x) {
    float u = x * x;
    float p = fmaf(0.019063f, u, -0.18852f);
    p = fmaf(p, u, 0.93106f);
    float r = x * p;
    return __builtin_amdgcn_fmed3f(r, -1.0f, 1.0f);
}
static __device__ __forceinline__ short8 pack_bf8(float4 a, float4 b) {
    short8 r;
    r[0] = (short)f2bf(a.x); r[1] = (short)f2bf(a.y);
    r[2] = (short)f2bf(a.z); r[3] = (short)f2bf(a.w);
    r[4] = (short)f2bf(b.x); r[5] = (short)f2bf(b.y);
    r[6] = (short)f2bf(b.z); r[7] = (short)f2bf(b.w);
    return r;
}

// ---------------------------------------------------------------------------
// prep_transpose: 7 weight planes (ih_r/z/n, hh_r/z/n, q) 256x256 fp32 ->
// transposed bf16-pair planes P2[c2][j]. 112 blocks.
// ---------------------------------------------------------------------------
__global__ void prep_transpose(const float* __restrict__ W_ih,
                               const float* __restrict__ W_hh,
                               const float* __restrict__ Wq,
                               uint_t* __restrict__ planes) {
    __shared__ float lds[64][65];
    const int p = blockIdx.x >> 4, tile = blockIdx.x & 15;
    const int j0 = (tile >> 2) * 64, c0 = (tile & 3) * 64;
    const float* src;
    if (p < 3)      src = W_ih + (size_t)p * 65536;
    else if (p < 6) src = W_hh + (size_t)(p - 3) * 65536;
    else            src = Wq;
    uint_t* dst = planes + (size_t)p * 32768;
    const int tid = threadIdx.x;
#pragma unroll
    for (int p4 = 0; p4 < 4; ++p4) {
        int i = p4 * 256 + tid;
        int jj = i >> 4, cc4 = (i & 15) * 4;
        float4 v = *((const float4*)&src[(size_t)(j0 + jj) * 256 + c0 + cc4]);
        lds[jj][cc4]     = v.x;
        lds[jj][cc4 + 1] = v.y;
        lds[jj][cc4 + 2] = v.z;
        lds[jj][cc4 + 3] = v.w;
    }
    __syncthreads();
#pragma unroll
    for (int p8 = 0; p8 < 8; ++p8) {
        int i = p8 * 256 + tid;
        int c2 = i >> 6, j = i & 63;
        float lo = lds[j][c2 * 2], hi = lds[j][c2 * 2 + 1];
        uint_t val = (uint_t)f2bf(lo) | ((uint_t)f2bf(hi) << 16);
        dst[(size_t)(c0 / 2 + c2) * 256 + j0 + j] = val;
    }
}

// ---------------------------------------------------------------------------
// prep_small: Wd -> bf16, mask output, AND NEG_INF-fill of the masked score
// region (s >= slen). grid = 5888*256 exactly (65536 + 131072 + 1310720).
// ---------------------------------------------------------------------------
__global__ void prep_small(const float* __restrict__ Wd, const int* __restrict__ slen,
                           ushort_t* __restrict__ Wd_bf, float* __restrict__ out_mask,
                           float* __restrict__ out_score) {
    int i = blockIdx.x * 256 + threadIdx.x;
    if (i < 65536) { Wd_bf[i] = f2bf(Wd[i]); return; }
    i -= 65536;
    if (i < B_ * S_) {
        int b = i >> 10, s = i & 1023;
        out_mask[i] = (s >= slen[b]) ? 1.0f : 0.0f;
        return;
    }
    i -= B_ * S_;
    // score fill: i indexes [T][B][S]
    int bs = i & (B_ * S_ - 1);
    int b = bs >> 10, s = bs & 1023;
    if (s >= slen[b]) out_score[i] = NEG_INF_;
}

// ---------------------------------------------------------------------------
// build_tiles: 1 block x 1024 threads. tid = (b,st); active if tile overlaps
// [0, slen[b]). Deterministic ballot + prefix-scan compaction into tlist.
// ---------------------------------------------------------------------------
__global__ __launch_bounds__(1024) void build_tiles(const int* __restrict__ slen,
                                                    int* __restrict__ tlist,
                                                    int* __restrict__ tcount) {
    const int tid = threadIdx.x;
    const int b = tid >> 3, st = tid & 7;
    const bool active = (st * 128) < slen[b];
    unsigned long long m = __ballot(active);
    const int lane = tid & 63, wv = tid >> 6;
    __shared__ int wbase[16];
    if (lane == 0) wbase[wv] = __popcll(m);
    __syncthreads();
    if (tid == 0) {
        int s = 0;
#pragma unroll
        for (int i = 0; i < 16; ++i) { int c = wbase[i]; wbase[i] = s; s += c; }
        *tcount = s;
    }
    __syncthreads();
    if (active) {
        unsigned long long below = (lane == 0) ? 0ull : (m << (64 - lane));
        int pos = wbase[wv] + __popcll(below);
        tlist[pos] = tid;
    }
}

// ---------------------------------------------------------------------------
// gru_all: 128 blocks x 512 threads, split-K, register-batched loads.
// (unchanged from R8/R10 -- part of the 179us config)
// ---------------------------------------------------------------------------
__global__ __launch_bounds__(512) void gru_all(
        const float* __restrict__ s0, const float* __restrict__ h0,
        const float* __restrict__ doc, const int* __restrict__ tgt,
        const uint_t* __restrict__ planes, const float* __restrict__ b_ih,
        const float* __restrict__ b_hh, const float* __restrict__ bq,
        float* __restrict__ targets) {
    __shared__ float xs[T_][256];
    __shared__ float hs[256];
    __shared__ float pr[256], pz[256], pn[256], pq[256];
    const int b = blockIdx.x;
    const int tid = threadIdx.x;
    const int j = tid & 255, half = tid >> 8;

    const uint_t* ihr = planes;
    const uint_t* ihz = planes + 32768;
    const uint_t* ihn = planes + 2 * 32768;
    const uint_t* hhr = planes + 3 * 32768;
    const uint_t* hhz = planes + 4 * 32768;
    const uint_t* hhn = planes + 5 * 32768;
    const uint_t* qT  = planes + 6 * 32768;

    for (int i = tid; i < 640; i += 512) {
        int t = i >> 6, c4 = i & 63;
        const float* src;
        if (t == 0) src = s0 + (size_t)b * H_;
        else {
            int idx = tgt[b * T_ + t - 1];
            if (idx < 0) idx = 0;
            src = doc + ((size_t)b * S_ + idx) * H_;
        }
        ((float4*)&xs[t][0])[c4] = ((const float4*)src)[c4];
    }
    if (half == 0) hs[j] = h0[(size_t)b * H_ + j];
    const float bhr = b_hh[j], bhz = b_hh[j + 256], bhn = b_hh[j + 512];
    const float bqj = bq[j];
    const float bihr = b_ih[j], bihz = b_ih[j + 256], bihn = b_ih[j + 512];
    __syncthreads();

    float g_r[5], g_z[5], g_n[5];
#pragma unroll
    for (int u = 0; u < 5; ++u) { g_r[u] = bihr; g_z[u] = bihz; g_n[u] = bihn; }
    const int tbase = half * 5;
#pragma unroll 1
    for (int bb = 0; bb < 16; ++bb) {
        uint_t wr8[8], wz8[8], wn8[8];
#pragma unroll
        for (int v = 0; v < 8; ++v) {
            int c2 = bb * 8 + v;
            wr8[v] = ihr[c2 * 256 + j];
            wz8[v] = ihz[c2 * 256 + j];
            wn8[v] = ihn[c2 * 256 + j];
        }
#pragma unroll
        for (int v = 0; v < 8; ++v) {
            int c2 = bb * 8 + v;
            float wr0 = bflo(wr8[v]), wr1 = bfhi(wr8[v]);
            float wz0 = bflo(wz8[v]), wz1 = bfhi(wz8[v]);
            float wn0 = bflo(wn8[v]), wn1 = bfhi(wn8[v]);
#pragma unroll
            for (int u = 0; u < 5; ++u) {
                float2 x2 = *((const float2*)&xs[tbase + u][c2 * 2]);
                g_r[u] = fmaf(wr0, x2.x, g_r[u]); g_r[u] = fmaf(wr1, x2.y, g_r[u]);
                g_z[u] = fmaf(wz0, x2.x, g_z[u]); g_z[u] = fmaf(wz1, x2.y, g_z[u]);
                g_n[u] = fmaf(wn0, x2.x, g_n[u]); g_n[u] = fmaf(wn1, x2.y, g_n[u]);
            }
        }
    }

    const int c2base = half * 64;
    const uint_t* hhr_h = hhr + (size_t)c2base * 256 + j;
    const uint_t* hhz_h = hhz + (size_t)c2base * 256 + j;
    const uint_t* hhn_h = hhn + (size_t)c2base * 256 + j;
    const uint_t* qT_h  = qT  + (size_t)c2base * 256 + j;

#pragma unroll
    for (int t = 0; t < T_; ++t) {
        const bool holder = (half == (t >= 5 ? 1 : 0));
        const int u = (t < 5) ? t : t - 5;
        float ar = 0.f, az = 0.f, an = 0.f;
#pragma unroll 1
        for (int bb = 0; bb < 8; ++bb) {
            uint_t wr8[8], wz8[8], wn8[8];
#pragma unroll
            for (int v = 0; v < 8; ++v) {
                int c2i = bb * 8 + v;
                wr8[v] = hhr_h[c2i * 256];
                wz8[v] = hhz_h[c2i * 256];
                wn8[v] = hhn_h[c2i * 256];
            }
#pragma unroll
            for (int v = 0; v < 8; ++v) {
                int c2i = bb * 8 + v;
                float2 h2 = *((const float2*)&hs[(c2base + c2i) * 2]);
                ar = fmaf(bflo(wr8[v]), h2.x, ar); ar = fmaf(bfhi(wr8[v]), h2.y, ar);
                az = fmaf(bflo(wz8[v]), h2.x, az); az = fmaf(bfhi(wz8[v]), h2.y, az);
                an = fmaf(bflo(wn8[v]), h2.x, an); an = fmaf(bfhi(wn8[v]), h2.y, an);
            }
        }
        if (!holder) { pr[j] = ar; pz[j] = az; pn[j] = an; }
        __syncthreads();
        if (holder) {
            float art = ar + pr[j] + bhr;
            float azt = az + pz[j] + bhz;
            float ant = an + pn[j] + bhn;
            float r = sigf(g_r[u] + art);
            float z = sigf(g_z[u] + azt);
            float n = tanh_acc(fmaf(r, ant, g_n[u]));
            float hold = hs[j];
            hs[j] = fmaf(z, hold - n, n);
        }
        __syncthreads();
        float q = 0.f;
#pragma unroll 1
        for (int bb = 0; bb < 4; ++bb) {
            uint_t wq16[16];
#pragma unroll
            for (int v = 0; v < 16; ++v)
                wq16[v] = qT_h[(bb * 16 + v) * 256];
#pragma unroll
            for (int v = 0; v < 16; ++v) {
                int c2i = bb * 16 + v;
                float2 h2 = *((const float2*)&hs[(c2base + c2i) * 2]);
                q = fmaf(bflo(wq16[v]), h2.x, q); q = fmaf(bfhi(wq16[v]), h2.y, q);
            }
        }
        if (!holder) pq[j] = q;
        __syncthreads();
        if (holder) targets[((size_t)t * B_ + b) * H_ + j] = q + pq[j] + bqj;
    }
}

// ---------------------------------------------------------------------------
// energy: R10 body (2-tile block, Wd prefetch pipeline, scalar tanh_fast),
// driven by the COMPACTED tile list: block bid handles tlist[bid] -> active
// tiles spread evenly over CUs (per-CU max = ceil(count/256) ~ 3 vs 4).
// Masked region already NEG_INF-filled by prep_small.
// D layout: col(lane&15)=s, row(g*4+rr)=k.
// ---------------------------------------------------------------------------
__global__ __launch_bounds__(256, 3) void energy_kernel(
        const float* __restrict__ doc, const ushort_t* __restrict__ Wd_bf,
        const float* __restrict__ targets, const float* __restrict__ bd,
        const float* __restrict__ Ws, const float* __restrict__ bs,
        const int* __restrict__ slenp, const int* __restrict__ tlist,
        const int* __restrict__ tcount, float* __restrict__ out) {
    __shared__ float tg[T_][256];
    __shared__ float ws_l[256], bd_l[256];
    const int bid = blockIdx.x;
    if (bid >= *tcount) return;
    const int tile = tlist[bid];
    const int b = tile >> 3, st = tile & 7;
    const int tid = threadIdx.x;

    const int slen = slenp[b];

    for (int i = tid; i < 640; i += 256) {
        int t = i >> 6, k4 = i & 63;
        ((float4*)&tg[t][0])[k4] = *((const float4*)&targets[((size_t)t * B_ + b) * H_ + k4 * 4]);
    }
    if (tid < 64) ((float4*)ws_l)[tid] = ((const float4*)Ws)[tid];
    else if (tid < 128) ((float4*)bd_l)[tid - 64] = ((const float4*)bd)[tid - 64];

    const int lane = tid & 63, w = tid >> 6;
    const int r16 = lane & 15, g = lane >> 4;

    const int s0_loc = st * 128 + w * 16 + r16;
    const float* drow0 = doc + ((size_t)b * S_ + s0_loc) * H_ + g * 8;
    const float* drow1 = drow0 + (size_t)64 * H_;
    short8 bdoc0[8], bdoc1[8];
#pragma unroll
    for (int ks = 0; ks < 8; ++ks) {
        float4 v0 = *((const float4*)(drow0 + ks * 32));
        float4 v1 = *((const float4*)(drow0 + ks * 32 + 4));
        bdoc0[ks] = pack_bf8(v0, v1);
        float4 u0 = *((const float4*)(drow1 + ks * 32));
        float4 u1 = *((const float4*)(drow1 + ks * 32 + 4));
        bdoc1[ks] = pack_bf8(u0, u1);
    }
    __syncthreads();

    float e0[T_], e1[T_];
#pragma unroll
    for (int t = 0; t < T_; ++t) { e0[t] = 0.f; e1[t] = 0.f; }

    const ushort_t* wbase = Wd_bf + (size_t)r16 * H_ + g * 8;
    const int kq = g * 4;

    // prologue: load nt=0 fragments
    short8 awd[8];
#pragma unroll
    for (int ks = 0; ks < 8; ++ks) awd[ks] = *((const short8*)(wbase + ks * 32));

#pragma unroll 1
    for (int nt = 0; nt < 16; ++nt) {
        const int k0 = nt * 16 + kq;

        // prefetch nt+1's fragments BEFORE compute/epilogue (latency hides)
        short8 awn[8];
        if (nt < 15) {
            const ushort_t* wnext = wbase + (size_t)((nt + 1) * 16) * H_;
#pragma unroll
            for (int ks = 0; ks < 8; ++ks) awn[ks] = *((const short8*)(wnext + ks * 32));
        }

        f32x4 bd4 = *((const f32x4*)&bd_l[k0]);
        f32x4 a00 = bd4;
        f32x4 a01 = {0.f, 0.f, 0.f, 0.f};
        f32x4 a10 = bd4;
        f32x4 a11 = {0.f, 0.f, 0.f, 0.f};
#pragma unroll
        for (int ks = 0; ks < 4; ++ks) {
            a00 = __builtin_amdgcn_mfma_f32_16x16x32_bf16(awd[ks],     bdoc0[ks],     a00, 0, 0, 0);
            a01 = __builtin_amdgcn_mfma_f32_16x16x32_bf16(awd[ks + 4], bdoc0[ks + 4], a01, 0, 0, 0);
            a10 = __builtin_amdgcn_mfma_f32_16x16x32_bf16(awd[ks],     bdoc1[ks],     a10, 0, 0, 0);
            a11 = __builtin_amdgcn_mfma_f32_16x16x32_bf16(awd[ks + 4], bdoc1[ks + 4], a11, 0, 0, 0);
        }
        f32x4 pA = a00 + a01;
        f32x4 pB = a10 + a11;
        f32x4 ws4 = *((const f32x4*)&ws_l[k0]);
#pragma unroll
        for (int t = 0; t < T_; ++t) {
            f32x4 tg4 = *((const f32x4*)&tg[t][k0]);
#pragma unroll
            for (int rr = 0; rr < 4; ++rr) {
                e0[t] = fmaf(tanh_fast(pA[rr] + tg4[rr]), ws4[rr], e0[t]);
                e1[t] = fmaf(tanh_fast(pB[rr] + tg4[rr]), ws4[rr], e1[t]);
            }
        }

        // rotate prefetched fragments in
#pragma unroll
        for (int ks = 0; ks < 8; ++ks) awd[ks] = awn[ks];
    }

    // reduce over g (lane bits 4,5)
#pragma unroll
    for (int t = 0; t < T_; ++t) {
        e0[t] += __shfl_xor(e0[t], 16);
        e0[t] += __shfl_xor(e0[t], 32);
        e1[t] += __shfl_xor(e1[t], 16);
        e1[t] += __shfl_xor(e1[t], 32);
    }

    const float bs0 = bs[0];
    const bool pad0 = (s0_loc >= slen);
    const bool pad1 = (s0_loc + 64 >= slen);
    float* obase = out + (size_t)b * S_ + s0_loc;
#pragma unroll
    for (int tt = g; tt < T_; tt += 4) {
        if (!pad0) obase[(size_t)tt * B_ * S_]      = e0[tt] + bs0;
        if (!pad1) obase[(size_t)tt * B_ * S_ + 64] = e1[tt] + bs0;
    }
}

// ---------------------------------------------------------------------------
extern "C" void kernel_launch(void* const* d_in, const int* in_sizes, int n_in,
                              void* d_out, int out_size, void* d_ws, size_t ws_size,
                              hipStream_t stream) {
    (void)in_sizes; (void)n_in; (void)out_size; (void)ws_size;
    const float* s0   = (const float*)d_in[0];
    const float* h0   = (const float*)d_in[1];
    const float* doc  = (const float*)d_in[2];
    const float* W_ih = (const float*)d_in[3];
    const float* W_hh = (const float*)d_in[4];
    const float* b_ih = (const float*)d_in[5];
    const float* b_hh = (const float*)d_in[6];
    const float* Wq   = (const float*)d_in[7];
    const float* bq   = (const float*)d_in[8];
    const float* Wd   = (const float*)d_in[9];
    const float* bd   = (const float*)d_in[10];
    const float* Ws   = (const float*)d_in[11];
    const float* bs   = (const float*)d_in[12];
    const int*   tgt  = (const int*)d_in[13];
    const int*   slen = (const int*)d_in[14];

    float* out_score = (float*)d_out;                       // [10][128][1024]
    float* out_mask  = out_score + T_ * B_ * S_;            // [128][1024]

    char* ws = (char*)d_ws;
    uint_t*   planes  = (uint_t*)(ws + 0);                  //  917504 B
    ushort_t* Wd_bf   = (ushort_t*)(ws + 917504);           //  131072 B
    float*    targets = (float*)(ws + 1048576);             // 1310720 B
    int*      tlist   = (int*)(ws + 2359296);               //    4096 B
    int*      tcount  = (int*)(ws + 2363392);               //       4 B

    prep_transpose<<<112, 256, 0, stream>>>(W_ih, W_hh, Wq, planes);
    prep_small<<<5888, 256, 0, stream>>>(Wd, slen, Wd_bf, out_mask, out_score);
    build_tiles<<<1, 1024, 0, stream>>>(slen, tlist, tcount);
    gru_all<<<128, 512, 0, stream>>>(s0, h0, doc, tgt, planes, b_ih, b_hh, bq, targets);
    energy_kernel<<<1024, 256, 0, stream>>>(doc, Wd_bf, targets, bd, Ws, bs, slen,
                                            tlist, tcount, out_score);
}